// Round 16
// baseline (3603.132 us; speedup 1.0000x reference)
//
#include <hip/hip_runtime.h>
#include <stdint.h>

typedef unsigned short u16;
typedef unsigned int u32;
typedef __attribute__((ext_vector_type(2))) float f32x2;
typedef __attribute__((ext_vector_type(4))) float f32x4;
typedef __attribute__((ext_vector_type(8))) _Float16 f16x8;

#define NBLK 256
#define SMAX 172
#define NSLOT 22
#define HS_OFF 4194304
#define CS_OFF 4210688
#define FH_OFF 0      // [l][mb][w] : 2*2*16 = 64
#define FR_OFF 384    // [l][b]     : 64

struct SmemA { u16 hi[16][520]; u16 lo[16][520]; float gates[4][16][17]; float c[16][17]; };
struct SmemS { float sc[SMAX]; float wv[SMAX]; float red[16]; float redC[8][256]; float hoSh[256]; };
union Smem { SmemA a; SmemS s; };

struct Params {
  const u16 *wt0h, *wt0l, *wt1h, *wt1l;
  const float *bias0, *bias1;
  const float *x;
  float *raw0, *ref0, *raw1;
  float *rr;            // epoch-tagged h ring (GEMM self-loop)
  float *mzT, *ctxr;    // self-tagged: mzT {m,tag,Z,tag,wlast,tag,pad2}; ctxr {ctx,tag}
  u32 *flags;
  float *out;   // fp32 — reference's output dtype
};

// ===== coherence-point access: FUSED loads + wait in ONE asm block =====
__device__ __forceinline__ void ld1s(const float* p, float& a){
  asm volatile("global_load_dword %0, %1, off sc0 sc1\n\ts_waitcnt vmcnt(0)"
               : "=&v"(a) : "v"(p) : "memory");
}
__device__ __forceinline__ void ld2v(const float* p0,const float* p1, f32x4&a,f32x4&b){
  asm volatile("global_load_dwordx4 %0, %2, off sc0 sc1\n\t"
               "global_load_dwordx4 %1, %3, off sc0 sc1\n\t"
               "s_waitcnt vmcnt(0)"
               : "=&v"(a),"=&v"(b) : "v"(p0),"v"(p1) : "memory");
}
__device__ __forceinline__ void ld4v(const float* p0,const float* p1,const float* p2,const float* p3,
                                     f32x4&a,f32x4&b,f32x4&c,f32x4&d){
  asm volatile("global_load_dwordx4 %0, %4, off sc0 sc1\n\t"
               "global_load_dwordx4 %1, %5, off sc0 sc1\n\t"
               "global_load_dwordx4 %2, %6, off sc0 sc1\n\t"
               "global_load_dwordx4 %3, %7, off sc0 sc1\n\t"
               "s_waitcnt vmcnt(0)"
               : "=&v"(a),"=&v"(b),"=&v"(c),"=&v"(d)
               : "v"(p0),"v"(p1),"v"(p2),"v"(p3) : "memory");
}
__device__ __forceinline__ void ld8v(const float* p0,const float* p1,const float* p2,const float* p3,
                                     const float* p4,const float* p5,const float* p6,const float* p7,
                                     f32x4&a,f32x4&b,f32x4&c,f32x4&d,f32x4&e,f32x4&f,f32x4&g,f32x4&h){
  asm volatile("global_load_dwordx4 %0, %8, off sc0 sc1\n\t"
               "global_load_dwordx4 %1, %9, off sc0 sc1\n\t"
               "global_load_dwordx4 %2, %10, off sc0 sc1\n\t"
               "global_load_dwordx4 %3, %11, off sc0 sc1\n\t"
               "global_load_dwordx4 %4, %12, off sc0 sc1\n\t"
               "global_load_dwordx4 %5, %13, off sc0 sc1\n\t"
               "global_load_dwordx4 %6, %14, off sc0 sc1\n\t"
               "global_load_dwordx4 %7, %15, off sc0 sc1\n\t"
               "s_waitcnt vmcnt(0)"
               : "=&v"(a),"=&v"(b),"=&v"(c),"=&v"(d),"=&v"(e),"=&v"(f),"=&v"(g),"=&v"(h)
               : "v"(p0),"v"(p1),"v"(p2),"v"(p3),"v"(p4),"v"(p5),"v"(p6),"v"(p7) : "memory");
}
__device__ __forceinline__ void ld12v(const float* p0,const float* p1,const float* p2,const float* p3,
                                      const float* p4,const float* p5,const float* p6,const float* p7,
                                      const float* p8,const float* p9,const float* pa,const float* pb,
                                      f32x4&a,f32x4&b,f32x4&c,f32x4&d,f32x4&e,f32x4&f,
                                      f32x4&g,f32x4&h,f32x4&i,f32x4&j,f32x4&k,f32x4&l){
  asm volatile("global_load_dwordx4 %0, %12, off sc0 sc1\n\t"
               "global_load_dwordx4 %1, %13, off sc0 sc1\n\t"
               "global_load_dwordx4 %2, %14, off sc0 sc1\n\t"
               "global_load_dwordx4 %3, %15, off sc0 sc1\n\t"
               "global_load_dwordx4 %4, %16, off sc0 sc1\n\t"
               "global_load_dwordx4 %5, %17, off sc0 sc1\n\t"
               "global_load_dwordx4 %6, %18, off sc0 sc1\n\t"
               "global_load_dwordx4 %7, %19, off sc0 sc1\n\t"
               "global_load_dwordx4 %8, %20, off sc0 sc1\n\t"
               "global_load_dwordx4 %9, %21, off sc0 sc1\n\t"
               "global_load_dwordx4 %10, %22, off sc0 sc1\n\t"
               "global_load_dwordx4 %11, %23, off sc0 sc1\n\t"
               "s_waitcnt vmcnt(0)"
               : "=&v"(a),"=&v"(b),"=&v"(c),"=&v"(d),"=&v"(e),"=&v"(f),
                 "=&v"(g),"=&v"(h),"=&v"(i),"=&v"(j),"=&v"(k),"=&v"(l)
               : "v"(p0),"v"(p1),"v"(p2),"v"(p3),"v"(p4),"v"(p5),
                 "v"(p6),"v"(p7),"v"(p8),"v"(p9),"v"(pa),"v"(pb) : "memory");
}
// fused partial(tC)+combine+score loads (tC>=1); all cross-WG payloads self-tagged
__device__ __forceinline__ void ldPC(const float* c1p,const float* c2p,const float* mzap,const float* mzbp,const float* hcp,
                                     f32x2&c1, f32x2&c2, f32x4&mzA, f32x2&wlA, f32x4&mzB, f32x2&wlB, float&hrC){
  asm volatile("global_load_dwordx2 %0, %7, off sc0 sc1\n\t"
               "global_load_dwordx2 %1, %8, off sc0 sc1\n\t"
               "global_load_dwordx4 %2, %9, off sc0 sc1\n\t"
               "global_load_dwordx2 %3, %10, off sc0 sc1\n\t"
               "global_load_dwordx4 %4, %11, off sc0 sc1\n\t"
               "global_load_dwordx2 %5, %12, off sc0 sc1\n\t"
               "global_load_dword %6, %13, off sc0 sc1\n\t"
               "s_waitcnt vmcnt(0)"
               : "=&v"(c1),"=&v"(c2),"=&v"(mzA),"=&v"(wlA),"=&v"(mzB),"=&v"(wlB),"=&v"(hrC)
               : "v"(c1p),"v"(c2p),"v"(mzap),"v"(mzap+4),"v"(mzbp),"v"(mzbp+4),"v"(hcp) : "memory");
}
__device__ __forceinline__ void ldP2(const float* c1p,const float* c2p,const float* mzap,const float* mzbp,const float* hcp,
                                     const float* hp,
                                     f32x2&c1, f32x2&c2, f32x4&mzA, f32x2&wlA, f32x4&mzB, f32x2&wlB, float&hrC,
                                     f32x4&h0, f32x4&h1){
  asm volatile("global_load_dwordx2 %0, %9, off sc0 sc1\n\t"
               "global_load_dwordx2 %1, %10, off sc0 sc1\n\t"
               "global_load_dwordx4 %2, %11, off sc0 sc1\n\t"
               "global_load_dwordx2 %3, %12, off sc0 sc1\n\t"
               "global_load_dwordx4 %4, %13, off sc0 sc1\n\t"
               "global_load_dwordx2 %5, %14, off sc0 sc1\n\t"
               "global_load_dword %6, %15, off sc0 sc1\n\t"
               "global_load_dwordx4 %7, %16, off sc0 sc1\n\t"
               "global_load_dwordx4 %8, %17, off sc0 sc1\n\t"
               "s_waitcnt vmcnt(0)"
               : "=&v"(c1),"=&v"(c2),"=&v"(mzA),"=&v"(wlA),"=&v"(mzB),"=&v"(wlB),"=&v"(hrC),
                 "=&v"(h0),"=&v"(h1)
               : "v"(c1p),"v"(c2p),"v"(mzap),"v"(mzap+4),"v"(mzbp),"v"(mzbp+4),"v"(hcp),
                 "v"(hp),"v"(hp+4) : "memory");
}
__device__ __forceinline__ void ldP3(const float* c1p,const float* c2p,const float* mzap,const float* mzbp,const float* hcp,
                                     const float* hp,const float* rp,
                                     f32x2&c1, f32x2&c2, f32x4&mzA, f32x2&wlA, f32x4&mzB, f32x2&wlB, float&hrC,
                                     f32x4&h0, f32x4&h1, f32x4&r0, f32x4&r1){
  asm volatile("global_load_dwordx2 %0, %11, off sc0 sc1\n\t"
               "global_load_dwordx2 %1, %12, off sc0 sc1\n\t"
               "global_load_dwordx4 %2, %13, off sc0 sc1\n\t"
               "global_load_dwordx2 %3, %14, off sc0 sc1\n\t"
               "global_load_dwordx4 %4, %15, off sc0 sc1\n\t"
               "global_load_dwordx2 %5, %16, off sc0 sc1\n\t"
               "global_load_dword %6, %17, off sc0 sc1\n\t"
               "global_load_dwordx4 %7, %18, off sc0 sc1\n\t"
               "global_load_dwordx4 %8, %19, off sc0 sc1\n\t"
               "global_load_dwordx4 %9, %20, off sc0 sc1\n\t"
               "global_load_dwordx4 %10, %21, off sc0 sc1\n\t"
               "s_waitcnt vmcnt(0)"
               : "=&v"(c1),"=&v"(c2),"=&v"(mzA),"=&v"(wlA),"=&v"(mzB),"=&v"(wlB),"=&v"(hrC),
                 "=&v"(h0),"=&v"(h1),"=&v"(r0),"=&v"(r1)
               : "v"(c1p),"v"(c2p),"v"(mzap),"v"(mzap+4),"v"(mzbp),"v"(mzbp+4),"v"(hcp),
                 "v"(hp),"v"(hp+4),"v"(rp),"v"(rp+4) : "memory");
}
__device__ __forceinline__ void st_coh(float* p, float v){
  asm volatile("global_store_dword %0, %1, off sc0 sc1" :: "v"(p), "v"(v) : "memory");
}
__device__ __forceinline__ void st_coh2(float* p, f32x2 v){
  asm volatile("global_store_dwordx2 %0, %1, off sc0 sc1" :: "v"(p), "v"(v) : "memory");
}
__device__ __forceinline__ void st_coh4(float* p, f32x4 v){
  asm volatile("global_store_dwordx4 %0, %1, off sc0 sc1" :: "v"(p), "v"(v) : "memory");
}
__device__ __forceinline__ void st_cohU(u32* p, u32 v){
  asm volatile("global_store_dword %0, %1, off sc0 sc1" :: "v"(p), "v"(v) : "memory");
}
__device__ __forceinline__ void pollWait(const u32* p, u32 tgt, bool active){
  if (active) {
    int guard = 0;
    u32 v;
    do {
      asm volatile("global_load_dword %0, %1, off sc0 sc1\n\ts_waitcnt vmcnt(0)"
                   : "=&v"(v) : "v"(p) : "memory");
      if (v >= tgt) break;
      __builtin_amdgcn_s_sleep(1);
    } while (++guard < (1<<22));
  }
}
__device__ __forceinline__ void drainSyncFlag(u32* fp, u32 val, int tid){
  asm volatile("s_waitcnt vmcnt(0)" ::: "memory");
  __syncthreads();
  if (tid == 0) st_cohU(fp, val);
}

__device__ __forceinline__ bool ep8(const f32x4&a,const f32x4&b,const f32x4&c,const f32x4&d,
                                    const f32x4&e,const f32x4&f,const f32x4&g,const f32x4&h,u32 t){
  return __float_as_uint(a.y)==t && __float_as_uint(a.w)==t &&
         __float_as_uint(b.y)==t && __float_as_uint(b.w)==t &&
         __float_as_uint(c.y)==t && __float_as_uint(c.w)==t &&
         __float_as_uint(d.y)==t && __float_as_uint(d.w)==t &&
         __float_as_uint(e.y)==t && __float_as_uint(e.w)==t &&
         __float_as_uint(f.y)==t && __float_as_uint(f.w)==t &&
         __float_as_uint(g.y)==t && __float_as_uint(g.w)==t &&
         __float_as_uint(h.y)==t && __float_as_uint(h.w)==t;
}
// 8-tag check over ctx pair + both publishers' {m,tag,Z,tag}+{wlast,tag}
__device__ __forceinline__ bool tg8(const f32x2&c1,const f32x2&c2,
                                    const f32x4&mzA,const f32x2&wlA,
                                    const f32x4&mzB,const f32x2&wlB,u32 t){
  return __float_as_uint(c1.y)==t && __float_as_uint(c2.y)==t &&
         __float_as_uint(mzA.y)==t && __float_as_uint(mzA.w)==t && __float_as_uint(wlA.y)==t &&
         __float_as_uint(mzB.y)==t && __float_as_uint(mzB.w)==t && __float_as_uint(wlB.y)==t;
}

__device__ __forceinline__ float sigm(float x){ return 1.f/(1.f + __expf(-x)); }
__device__ __forceinline__ float tanh_f(float x){ return 1.f - 2.f/(__expf(2.f*x) + 1.f); }

__device__ __forceinline__ void cvt4(const f32x4 v, ushort4* oh, ushort4* ol){
  union { ushort4 u; _Float16 h[4]; } a, b;
  a.h[0]=(_Float16)v.x; a.h[1]=(_Float16)v.y; a.h[2]=(_Float16)v.z; a.h[3]=(_Float16)v.w;
  b.h[0]=(_Float16)(v.x-(float)a.h[0]); b.h[1]=(_Float16)(v.y-(float)a.h[1]);
  b.h[2]=(_Float16)(v.z-(float)a.h[2]); b.h[3]=(_Float16)(v.w-(float)a.h[3]);
  *oh = a.u; *ol = b.u;
}

// ================= GEMM+cell role (unchanged from R15) =================
template<int KBv, int L1E, int LAYER>
__device__ void runA(SmemA* A, const Params& P, int w, int mb){
  const u16* wthi = LAYER ? P.wt1h : P.wt0h;
  const u16* wtlo = LAYER ? P.wt1l : P.wt0l;
  const float* bs = LAYER ? P.bias1 : P.bias0;
  float* rawF = LAYER ? P.raw1 : P.raw0;
  const int tid = threadIdx.x;
  const int lane = tid & 63;
  const int g = tid >> 6;
  const int RL = LAYER*32 + mb*16;

  u32* fHw = P.flags + FH_OFF + (LAYER*2 + mb)*16 + w;
  u32* fR  = P.flags + FR_OFF + 0*32 + mb*16;

  f16x8 whi[KBv], wlo[KBv];
  {
    const int cb = g*16 + w;
    #pragma unroll
    for (int kb = 0; kb < KBv; ++kb) {
      whi[kb] = *(const f16x8*)(wthi + ((size_t)(cb*KBv + kb)*64 + lane)*8);
      wlo[kb] = *(const f16x8*)(wtlo + ((size_t)(cb*KBv + kb)*64 + lane)*8);
    }
  }
  const float bias = bs[g*256 + w*16 + (lane&15)];

  for (int i = tid; i < 16*17; i += 256) ((float*)A->c)[i] = 0.f;

  for (int t = 0; t < 512; ++t) {
    const int b2a = tid >> 5, cp = tid & 31;
    const int b2b = b2a + 8;
    const int slot = (t-1) & 3;
    const float* ra = P.rr + (((size_t)(RL+b2a)*4 + slot)*256 + cp*8)*2;
    const float* rb = P.rr + (((size_t)(RL+b2b)*4 + slot)*256 + cp*8)*2;
    const u32 epoch = (u32)t;
    f32x4 G0,G1,G2,G3,G4,G5,G6,G7;

    if (LAYER == 0) {
      f32x4 xv0 = *(const f32x4*)(P.x + ((size_t)((mb*16+b2a)*512 + t))*128 + cp*4);
      f32x4 xv1 = *(const f32x4*)(P.x + ((size_t)((mb*16+b2b)*512 + t))*128 + cp*4);
      if (t > 0) {
        int gu = 0;
        for (;;) {
          ld8v(ra, ra+4, ra+8, ra+12, rb, rb+4, rb+8, rb+12, G0,G1,G2,G3,G4,G5,G6,G7);
          if (ep8(G0,G1,G2,G3,G4,G5,G6,G7, epoch)) break;
          __builtin_amdgcn_s_sleep(1);
          if (++gu > (1<<20)) break;
        }
      } else {
        G0=G1=G2=G3=G4=G5=G6=G7=(f32x4){0.f,0.f,0.f,0.f};
      }
      cvt4(xv0, (ushort4*)&A->hi[b2a][cp*4], (ushort4*)&A->lo[b2a][cp*4]);
      cvt4(xv1, (ushort4*)&A->hi[b2b][cp*4], (ushort4*)&A->lo[b2b][cp*4]);
    } else {
      if (tid < 16) pollWait(fR + tid, (u32)(t+1), true);
      __syncthreads();
      const float* r0 = P.ref0 + ((size_t)((mb*16+b2a)*512 + t))*256 + cp*8;
      const float* r1 = P.ref0 + ((size_t)((mb*16+b2b)*512 + t))*256 + cp*8;
      f32x4 rv0, rv1, rv2, rv3;
      if (t > 0) {
        int gu = 0;
        for (;;) {
          ld12v(r0, r0+4, r1, r1+4, ra, ra+4, ra+8, ra+12, rb, rb+4, rb+8, rb+12,
                rv0, rv1, rv2, rv3, G0,G1,G2,G3,G4,G5,G6,G7);
          if (ep8(G0,G1,G2,G3,G4,G5,G6,G7, epoch)) break;
          __builtin_amdgcn_s_sleep(1);
          if (++gu > (1<<20)) break;
        }
      } else {
        ld4v(r0, r0+4, r1, r1+4, rv0, rv1, rv2, rv3);
        G0=G1=G2=G3=G4=G5=G6=G7=(f32x4){0.f,0.f,0.f,0.f};
      }
      cvt4(rv0, (ushort4*)&A->hi[b2a][cp*8],   (ushort4*)&A->lo[b2a][cp*8]);
      cvt4(rv1, (ushort4*)&A->hi[b2a][cp*8+4], (ushort4*)&A->lo[b2a][cp*8+4]);
      cvt4(rv2, (ushort4*)&A->hi[b2b][cp*8],   (ushort4*)&A->lo[b2b][cp*8]);
      cvt4(rv3, (ushort4*)&A->hi[b2b][cp*8+4], (ushort4*)&A->lo[b2b][cp*8+4]);
    }
    {
      const f32x4 hv0 = {G0.x,G0.z,G1.x,G1.z};
      const f32x4 hv1 = {G2.x,G2.z,G3.x,G3.z};
      const f32x4 hv2 = {G4.x,G4.z,G5.x,G5.z};
      const f32x4 hv3 = {G6.x,G6.z,G7.x,G7.z};
      cvt4(hv0, (ushort4*)&A->hi[b2a][L1E + cp*8],   (ushort4*)&A->lo[b2a][L1E + cp*8]);
      cvt4(hv1, (ushort4*)&A->hi[b2a][L1E + cp*8+4], (ushort4*)&A->lo[b2a][L1E + cp*8+4]);
      cvt4(hv2, (ushort4*)&A->hi[b2b][L1E + cp*8],   (ushort4*)&A->lo[b2b][L1E + cp*8]);
      cvt4(hv3, (ushort4*)&A->hi[b2b][L1E + cp*8+4], (ushort4*)&A->lo[b2b][L1E + cp*8+4]);
    }
    __syncthreads();
    f32x4 accA = {0.f,0.f,0.f,0.f}, accB = {0.f,0.f,0.f,0.f};
    const int ar = lane & 15;
    const int ks = (lane >> 4) * 8;
    #pragma unroll
    for (int kb = 0; kb < KBv; ++kb) {
      f16x8 ah = *(const f16x8*)(&A->hi[ar][kb*32 + ks]);
      f16x8 al = *(const f16x8*)(&A->lo[ar][kb*32 + ks]);
      accA = __builtin_amdgcn_mfma_f32_16x16x32_f16(ah, whi[kb], accA, 0,0,0);
      accB = __builtin_amdgcn_mfma_f32_16x16x32_f16(al, whi[kb], accB, 0,0,0);
      accA = __builtin_amdgcn_mfma_f32_16x16x32_f16(ah, wlo[kb], accA, 0,0,0);
      accB = __builtin_amdgcn_mfma_f32_16x16x32_f16(al, wlo[kb], accB, 0,0,0);
    }
    #pragma unroll
    for (int r = 0; r < 4; ++r)
      A->gates[g][(lane>>4)*4 + r][lane&15] = accA[r] + accB[r] + bias;
    __syncthreads();
    {
      const int bl = tid >> 4, hl = tid & 15;
      const float gi = A->gates[0][bl][hl];
      const float gf = A->gates[1][bl][hl];
      const float gg = A->gates[2][bl][hl];
      const float go = A->gates[3][bl][hl];
      const float iv = sigm(gi);
      const float fv = sigm(gf);
      const float gv = tanh_f(gg);
      const float ov = sigm(go);
      const float c = fv * A->c[bl][hl] + iv * gv;
      A->c[bl][hl] = c;
      const float hr = ov * tanh_f(c);
      const int bg = mb*16 + bl;
      f32x2 tag = { hr, __uint_as_float((u32)(t+1)) };
      st_coh2(P.rr + (((size_t)(RL+bl)*4 + (t&3))*256 + w*16 + hl)*2, tag);
      st_coh(rawF + ((size_t)(bg*512 + t))*256 + w*16 + hl, hr);
      if (t == 511) {
        P.out[HS_OFF + (LAYER*32 + bg)*256 + w*16 + hl] = hr;
        P.out[CS_OFF + (LAYER*32 + bg)*256 + w*16 + hl] = c;
      }
    }
    drainSyncFlag(fHw, (u32)(t+1), tid);
  }
}

// ================= merged scorer+combiner role (owner-exclusion fold) ========
// Partials at step tS EXCLUDE row tS-1 (owner publishes its weight wlast);
// consumers fold wlast*e*hoPrev locally (hoPrev thread-local, exact semantics).
// Order: combine(tC) [uses prev-step register partials] -> commit -> score(tS).
__device__ void runS(SmemS* S, const Params& P, int l, int b, int q){
  float* rawF = l ? P.raw1 : P.raw0;
  const int tid = threadIdx.x;
  const int sg = tid >> 5, li = tid & 31;
  const int wsg = (tid >> 6) << 1;
  const int mb = b >> 4;
  const int o1 = (q+1)%3, o2 = (q+2)%3;
  u32* fH  = P.flags + FH_OFF + (l*2 + mb)*16;
  u32* fRb = P.flags + FR_OFF + l*32 + b;
  const size_t l32b = (size_t)(l*32 + b);

  float pm = -1e30f, pZ = 0.f, pc = 0.f, pwl = 0.f;  // own partial (prev step)
  float hoPrev = 0.f;

  f32x4 rawA[NSLOT], rawB[NSLOT], refA[NSLOT], refB[NSLOT];
  #pragma unroll
  for (int sl = 0; sl < NSLOT; ++sl) {
    rawA[sl] = (f32x4){0.f,0.f,0.f,0.f}; rawB[sl] = (f32x4){0.f,0.f,0.f,0.f};
    refA[sl] = (f32x4){0.f,0.f,0.f,0.f}; refB[sl] = (f32x4){0.f,0.f,0.f,0.f};
  }

  for (int tS = 1; tS <= 512; ++tS) {
    const int tC = tS - 1;
    const bool doS = (tS <= 511);
    const bool gRaw = doS && (tC % 3 == q);

    // ---- poll h-row flags (GEMM) ----
    if (tid < 16) pollWait(fH + tid, doS ? (u32)(tS+1) : 512u, true);
    __syncthreads();

    const float* hp = rawF + ((size_t)(b*512 + tS))*256 + li*8;
    const float* rp = rawF + ((size_t)(b*512 + tC))*256 + li*8;
    f32x4 nr0, nr1, h0, h1;
    float ho;

    if (tC == 0) {
      float hrC;
      ld1s(rawF + (size_t)(b*512)*256 + tid, hrC);
      if (gRaw) ld4v(rp, rp+4, hp, hp+4, nr0, nr1, h0, h1);
      else      ld2v(hp, hp+4, h0, h1);
      ho = hrC;
    } else {
      const float* c1p  = P.ctxr + (((l32b*8 + (tC&7))*3 + o1)*256 + tid)*2;
      const float* c2p  = P.ctxr + (((l32b*8 + (tC&7))*3 + o2)*256 + tid)*2;
      const float* mzap = P.mzT + ((l32b*8 + (tC&7))*3 + o1)*8;
      const float* mzbp = P.mzT + ((l32b*8 + (tC&7))*3 + o2)*8;
      const float* hcp  = rawF + ((size_t)(b*512 + tC))*256 + tid;
      float hrC;
      f32x2 c1t, c2t, wlA, wlB;
      f32x4 mzA, mzB;
      const u32 tagC = (u32)tC;
      int gu = 0;
      if (doS) {
        if (gRaw) {
          for (;;) {
            ldP3(c1p, c2p, mzap, mzbp, hcp, hp, rp,
                 c1t, c2t, mzA, wlA, mzB, wlB, hrC, h0, h1, nr0, nr1);
            if (tg8(c1t, c2t, mzA, wlA, mzB, wlB, tagC)) break;
            __builtin_amdgcn_s_sleep(1);
            if (++gu > (1<<21)) break;
          }
        } else {
          for (;;) {
            ldP2(c1p, c2p, mzap, mzbp, hcp, hp,
                 c1t, c2t, mzA, wlA, mzB, wlB, hrC, h0, h1);
            if (tg8(c1t, c2t, mzA, wlA, mzB, wlB, tagC)) break;
            __builtin_amdgcn_s_sleep(1);
            if (++gu > (1<<21)) break;
          }
        }
      } else {
        for (;;) {
          ldPC(c1p, c2p, mzap, mzbp, hcp, c1t, c2t, mzA, wlA, mzB, wlB, hrC);
          if (tg8(c1t, c2t, mzA, wlA, mzB, wlB, tagC)) break;
          __builtin_amdgcn_s_sleep(1);
          if (++gu > (1<<21)) break;
        }
      }
      // ---- thread-local combine(tC) with owner-exclusion fold ----
      const float m1 = mzA.x, Z1 = mzA.z, wl1 = wlA.x;
      const float m2 = mzB.x, Z2 = mzB.z, wl2 = wlB.x;
      const float M  = fmaxf(pm, fmaxf(m1, m2));
      const float e0 = __expf(pm - M), e1 = __expf(m1 - M), e2 = __expf(m2 - M);
      const float Zt = pZ*e0 + Z1*e1 + Z2*e2;
      const float ctxs = pc*e0 + c1t.x*e1 + c2t.x*e2;
      const int qlast = (tC-1) % 3;       // owner of excluded row tC-1
      const float wsel = (qlast == q)  ? pwl*e0 :
                         (qlast == o1) ? wl1*e1 : wl2*e2;
      ho = hrC + (ctxs + wsel*hoPrev) / Zt;
    }
    hoPrev = ho;
    S->hoSh[tid] = ho;
    if (q == 0) {
      if (l == 0) st_coh(P.ref0 + ((size_t)(b*512 + tC))*256 + tid, ho);
      else        P.out[((size_t)(b*512 + tC))*256 + tid] = ho;
    }
    __syncthreads();
    // owner commits raw(tC) + ho(tC) into register history
    if (gRaw) {
      const int iN = tC / 3;
      const f32x4 f0 = *(const f32x4*)&S->hoSh[li*8];
      const f32x4 f1 = *(const f32x4*)&S->hoSh[li*8 + 4];
      if (sg == (iN & 7)) {
        const int slN = iN >> 3;
        #pragma unroll
        for (int sl = 0; sl < NSLOT; ++sl)
          if (sl == slN) { rawA[sl] = nr0; rawB[sl] = nr1; refA[sl] = f0; refB[sl] = f1; }
      }
    }
    if (q == 0 && l == 0) drainSyncFlag(fRb, (u32)(tC+1), tid);  // release L1 early

    // ---- score step tS + publish self-tagged partials (excl. row tC) ----
    if (doS) {
      const int n = (tS-1 >= q) ? ((tS-1-q)/3 + 1) : 0;
      const int nctx = n - (gRaw ? 1 : 0);   // owner's newest row excluded
      #pragma unroll
      for (int sl = 0; sl < NSLOT; ++sl) {
        if (sl*8 + wsg < n) {
          const int i = sl*8 + sg;
          float sum = rawA[sl].x*h0.x + rawA[sl].y*h0.y + rawA[sl].z*h0.z + rawA[sl].w*h0.w
                    + rawB[sl].x*h1.x + rawB[sl].y*h1.y + rawB[sl].z*h1.z + rawB[sl].w*h1.w;
          #pragma unroll
          for (int mm = 16; mm; mm >>= 1) sum += __shfl_xor(sum, mm, 32);
          if (i < n && li == 0) S->sc[i] = sum * 0.0625f;
        }
      }
      __syncthreads();
      if (tid < 64) {
        const float s0 = (tid     < n) ? S->sc[tid]     : -1e30f;
        const float s1 = (tid+64  < n) ? S->sc[tid+64]  : -1e30f;
        const float s2 = (tid+128 < n) ? S->sc[tid+128] : -1e30f;
        float mx = fmaxf(s0, fmaxf(s1, s2));
        #pragma unroll
        for (int mm = 32; mm; mm >>= 1) mx = fmaxf(mx, __shfl_xor(mx, mm, 64));
        const float e0 = (tid     < n) ? __expf(s0 - mx) : 0.f;
        const float e1 = (tid+64  < n) ? __expf(s1 - mx) : 0.f;
        const float e2 = (tid+128 < n) ? __expf(s2 - mx) : 0.f;
        if (tid     < n) S->wv[tid]     = e0;
        if (tid+64  < n) S->wv[tid+64]  = e1;
        if (tid+128 < n) S->wv[tid+128] = e2;
        float zs = e0 + e1 + e2;
        #pragma unroll
        for (int mm = 32; mm; mm >>= 1) zs += __shfl_xor(zs, mm, 64);
        if (tid == 0) { S->red[0] = mx; S->red[1] = zs; }
      }
      __syncthreads();
      const float m = S->red[0], Zs = S->red[1];
      const float wlast = (gRaw && n > 0) ? S->wv[n-1] : 0.f;
      f32x4 a0 = {0.f,0.f,0.f,0.f}, a1 = {0.f,0.f,0.f,0.f};
      #pragma unroll
      for (int sl = 0; sl < NSLOT; ++sl) {
        if (sl*8 + wsg < nctx) {
          const int i = sl*8 + sg;
          if (i < nctx) {
            const float wv = S->wv[i];
            a0.x += wv*refA[sl].x; a0.y += wv*refA[sl].y; a0.z += wv*refA[sl].z; a0.w += wv*refA[sl].w;
            a1.x += wv*refB[sl].x; a1.y += wv*refB[sl].y; a1.z += wv*refB[sl].z; a1.w += wv*refB[sl].w;
          }
        }
      }
      *(f32x4*)&S->redC[sg][li*8]     = a0;
      *(f32x4*)&S->redC[sg][li*8 + 4] = a1;
      __syncthreads();
      float cacc = 0.f;
      #pragma unroll
      for (int g2 = 0; g2 < 8; ++g2) cacc += S->redC[g2][tid];

      const float tagF = __uint_as_float((u32)tS);
      if (tid == 0) {
        float* mzw = P.mzT + ((l32b*8 + (tS&7))*3 + q)*8;
        st_coh4(mzw, (f32x4){ m, tagF, Zs, tagF });
        st_coh2(mzw + 4, (f32x2){ wlast, tagF });
      }
      st_coh2(P.ctxr + (((l32b*8 + (tS&7))*3 + q)*256 + tid)*2, (f32x2){ cacc, tagF });
      pm = m; pZ = Zs; pc = cacc; pwl = wlast;
    }
  }
}

__attribute__((amdgpu_waves_per_eu(1, 1)))
__global__ void __launch_bounds__(256) mainK(Params P){
  __shared__ Smem sm;
  const int blk = blockIdx.x;
  if (blk < 64) {
    const int l = blk >> 5, r = blk & 31, w = r >> 1, mb = r & 1;
    if (l == 0) runA<12,128,0>(&sm.a, P, w, mb);
    else        runA<16,256,1>(&sm.a, P, w, mb);
  } else {
    const int a = blk - 64, q = a >> 6, lb = a & 63, l = lb >> 5, b = lb & 31;
    runS(&sm.s, P, l, b, q);
  }
}

// ---- prep: weights (Dekker split), bias, zero flags + all tagged rings ----
__global__ void prepK(const float* Wih0, const float* Whh0, const float* bih0, const float* bhh0,
                      const float* Wih1, const float* Whh1, const float* bih1, const float* bhh1,
                      u16* wt0h, u16* wt0l, u16* wt1h, u16* wt1l,
                      float* bias0, float* bias1, u32* flags, float* rr, float* ctxr, float* mzT)
{
  const int np = gridDim.x * blockDim.x;
  const int g0 = blockIdx.x * blockDim.x + threadIdx.x;
  for (int i = g0; i < 64*12*512; i += np) {
    const int cb = i / (12*512), rem = i % (12*512);
    const int kb = rem / 512, r2 = rem % 512;
    const int lane = r2 >> 3, e = r2 & 7;
    const int j = cb*16 + (lane & 15);
    const int k = kb*32 + ((lane >> 4) << 3) + e;
    const float v = (k < 128) ? Wih0[j*128 + k] : Whh0[j*256 + (k - 128)];
    _Float16 h = (_Float16)v; _Float16 lo = (_Float16)(v - (float)h);
    u16 hb, lb; __builtin_memcpy(&hb,&h,2); __builtin_memcpy(&lb,&lo,2);
    wt0h[i] = hb; wt0l[i] = lb;
  }
  for (int i = g0; i < 64*16*512; i += np) {
    const int cb = i / (16*512), rem = i % (16*512);
    const int kb = rem / 512, r2 = rem % 512;
    const int lane = r2 >> 3, e = r2 & 7;
    const int j = cb*16 + (lane & 15);
    const int k = kb*32 + ((lane >> 4) << 3) + e;
    const float v = (k < 256) ? Wih1[j*256 + k] : Whh1[j*256 + (k - 256)];
    _Float16 h = (_Float16)v; _Float16 lo = (_Float16)(v - (float)h);
    u16 hb, lb; __builtin_memcpy(&hb,&h,2); __builtin_memcpy(&lb,&lo,2);
    wt1h[i] = hb; wt1l[i] = lb;
  }
  for (int i = g0; i < 1024; i += np) { bias0[i] = bih0[i] + bhh0[i]; bias1[i] = bih1[i] + bhh1[i]; }
  for (int i = g0; i < 1024; i += np) flags[i] = 0u;
  for (int i = g0; i < 64*4*256*2; i += np) rr[i] = 0.f;
  for (int i = g0; i < 64*8*3*256*2; i += np) ctxr[i] = 0.f;
  for (int i = g0; i < 64*8*3*8; i += np) mzT[i] = 0.f;
}

extern "C" void kernel_launch(void* const* d_in, const int* in_sizes, int n_in,
                              void* d_out, int out_size, void* d_ws, size_t ws_size,
                              hipStream_t stream)
{
  const float* x    = (const float*)d_in[0];
  const float* Wih0 = (const float*)d_in[1];
  const float* Whh0 = (const float*)d_in[2];
  const float* bih0 = (const float*)d_in[3];
  const float* bhh0 = (const float*)d_in[4];
  const float* Wih1 = (const float*)d_in[5];
  const float* Whh1 = (const float*)d_in[6];
  const float* bih1 = (const float*)d_in[7];
  const float* bhh1 = (const float*)d_in[8];

  char* base = (char*)d_ws;
  size_t off = 0;
  auto carve = [&](size_t bytes)->char* { char* p = base + off; off = (off + bytes + 255) & ~(size_t)255; return p; };
  u16*   wt0h  = (u16*)  carve((size_t)64*12*512*2);
  u16*   wt0l  = (u16*)  carve((size_t)64*12*512*2);
  u16*   wt1h  = (u16*)  carve((size_t)64*16*512*2);
  u16*   wt1l  = (u16*)  carve((size_t)64*16*512*2);
  float* bias0 = (float*)carve(1024*4);
  float* bias1 = (float*)carve(1024*4);
  float* raw0  = (float*)carve((size_t)32*512*256*4);
  float* ref0  = (float*)carve((size_t)32*512*256*4);
  float* raw1  = (float*)carve((size_t)32*512*256*4);
  float* ctxr  = (float*)carve((size_t)2*32*8*3*256*2*4);   // tagged float2
  float* mzT   = (float*)carve((size_t)2*32*8*3*8*4);       // {m,t,Z,t,wl,t,pad2}
  u32*   flags = (u32*)  carve(1024*4);
  float* rr    = (float*)carve((size_t)64*4*256*2*4);
  if (off > ws_size) return;  // workspace too small -> fail loudly

  prepK<<<dim3(1024), dim3(256), 0, stream>>>(Wih0,Whh0,bih0,bhh0,Wih1,Whh1,bih1,bhh1,
                                              wt0h,wt0l,wt1h,wt1l,bias0,bias1,flags,rr,ctxr,mzT);

  Params P;
  P.wt0h=wt0h; P.wt0l=wt0l; P.wt1h=wt1h; P.wt1l=wt1l;
  P.bias0=bias0; P.bias1=bias1; P.x=x;
  P.raw0=raw0; P.ref0=ref0; P.raw1=raw1;
  P.rr=rr; P.mzT=mzT; P.ctxr=ctxr; P.flags=flags; P.out=(float*)d_out;

  void* args[] = { &P };
  hipError_t e = hipLaunchCooperativeKernel((void*)mainK, dim3(NBLK), dim3(256), args, 0, stream);
  if (e != hipSuccess) {
    mainK<<<dim3(NBLK), dim3(256), 0, stream>>>(P);
  }
}

// Round 17
// 3474.818 us; speedup vs baseline: 1.0369x; 1.0369x over previous
//
#include <hip/hip_runtime.h>
#include <stdint.h>

typedef unsigned short u16;
typedef unsigned int u32;
typedef __attribute__((ext_vector_type(2))) float f32x2;
typedef __attribute__((ext_vector_type(4))) float f32x4;
typedef __attribute__((ext_vector_type(8))) _Float16 f16x8;

#define NBLK 256
#define SMAX 172
#define NSLOT 22
#define HS_OFF 4194304
#define CS_OFF 4210688
// flag regions (u32 indices into P.flags)
#define FH_OFF 0      // [l][mb][w] : 2*2*16 = 64
#define FR_OFF 384    // [l][b]     : 64

struct SmemA { u16 hi[16][520]; u16 lo[16][520]; float gates[4][16][17]; float c[16][17]; };
struct SmemS { float sc[SMAX]; float wv[SMAX]; float red[16]; float redC[8][256]; float hoSh[256]; };
union Smem { SmemA a; SmemS s; };

struct Params {
  const u16 *wt0h, *wt0l, *wt1h, *wt1l;
  const float *bias0, *bias1;
  const float *x;
  float *raw0, *ref0, *raw1;
  float *rr;            // epoch-tagged h ring (GEMM self-loop)
  float *mzT, *ctxr;    // self-tagged partials: mzT float4{m,tag,Z,tag}, ctxr float2{ctx,tag}
  u32 *flags;
  float *out;   // fp32 — reference's output dtype
};

// ===== coherence-point (IF$) access: FUSED loads + wait in ONE asm block =====
__device__ __forceinline__ void ld1s(const float* p, float& a){
  asm volatile("global_load_dword %0, %1, off sc0 sc1\n\ts_waitcnt vmcnt(0)"
               : "=&v"(a) : "v"(p) : "memory");
}
__device__ __forceinline__ void ld2v(const float* p0,const float* p1, f32x4&a,f32x4&b){
  asm volatile("global_load_dwordx4 %0, %2, off sc0 sc1\n\t"
               "global_load_dwordx4 %1, %3, off sc0 sc1\n\t"
               "s_waitcnt vmcnt(0)"
               : "=&v"(a),"=&v"(b) : "v"(p0),"v"(p1) : "memory");
}
__device__ __forceinline__ void ld4v(const float* p0,const float* p1,const float* p2,const float* p3,
                                     f32x4&a,f32x4&b,f32x4&c,f32x4&d){
  asm volatile("global_load_dwordx4 %0, %4, off sc0 sc1\n\t"
               "global_load_dwordx4 %1, %5, off sc0 sc1\n\t"
               "global_load_dwordx4 %2, %6, off sc0 sc1\n\t"
               "global_load_dwordx4 %3, %7, off sc0 sc1\n\t"
               "s_waitcnt vmcnt(0)"
               : "=&v"(a),"=&v"(b),"=&v"(c),"=&v"(d)
               : "v"(p0),"v"(p1),"v"(p2),"v"(p3) : "memory");
}
__device__ __forceinline__ void ld8v(const float* p0,const float* p1,const float* p2,const float* p3,
                                     const float* p4,const float* p5,const float* p6,const float* p7,
                                     f32x4&a,f32x4&b,f32x4&c,f32x4&d,f32x4&e,f32x4&f,f32x4&g,f32x4&h){
  asm volatile("global_load_dwordx4 %0, %8, off sc0 sc1\n\t"
               "global_load_dwordx4 %1, %9, off sc0 sc1\n\t"
               "global_load_dwordx4 %2, %10, off sc0 sc1\n\t"
               "global_load_dwordx4 %3, %11, off sc0 sc1\n\t"
               "global_load_dwordx4 %4, %12, off sc0 sc1\n\t"
               "global_load_dwordx4 %5, %13, off sc0 sc1\n\t"
               "global_load_dwordx4 %6, %14, off sc0 sc1\n\t"
               "global_load_dwordx4 %7, %15, off sc0 sc1\n\t"
               "s_waitcnt vmcnt(0)"
               : "=&v"(a),"=&v"(b),"=&v"(c),"=&v"(d),"=&v"(e),"=&v"(f),"=&v"(g),"=&v"(h)
               : "v"(p0),"v"(p1),"v"(p2),"v"(p3),"v"(p4),"v"(p5),"v"(p6),"v"(p7) : "memory");
}
__device__ __forceinline__ void ld12v(const float* p0,const float* p1,const float* p2,const float* p3,
                                      const float* p4,const float* p5,const float* p6,const float* p7,
                                      const float* p8,const float* p9,const float* pa,const float* pb,
                                      f32x4&a,f32x4&b,f32x4&c,f32x4&d,f32x4&e,f32x4&f,
                                      f32x4&g,f32x4&h,f32x4&i,f32x4&j,f32x4&k,f32x4&l){
  asm volatile("global_load_dwordx4 %0, %12, off sc0 sc1\n\t"
               "global_load_dwordx4 %1, %13, off sc0 sc1\n\t"
               "global_load_dwordx4 %2, %14, off sc0 sc1\n\t"
               "global_load_dwordx4 %3, %15, off sc0 sc1\n\t"
               "global_load_dwordx4 %4, %16, off sc0 sc1\n\t"
               "global_load_dwordx4 %5, %17, off sc0 sc1\n\t"
               "global_load_dwordx4 %6, %18, off sc0 sc1\n\t"
               "global_load_dwordx4 %7, %19, off sc0 sc1\n\t"
               "global_load_dwordx4 %8, %20, off sc0 sc1\n\t"
               "global_load_dwordx4 %9, %21, off sc0 sc1\n\t"
               "global_load_dwordx4 %10, %22, off sc0 sc1\n\t"
               "global_load_dwordx4 %11, %23, off sc0 sc1\n\t"
               "s_waitcnt vmcnt(0)"
               : "=&v"(a),"=&v"(b),"=&v"(c),"=&v"(d),"=&v"(e),"=&v"(f),
                 "=&v"(g),"=&v"(h),"=&v"(i),"=&v"(j),"=&v"(k),"=&v"(l)
               : "v"(p0),"v"(p1),"v"(p2),"v"(p3),"v"(p4),"v"(p5),
                 "v"(p6),"v"(p7),"v"(p8),"v"(p9),"v"(pa),"v"(pb) : "memory");
}
// merged combine+score loads; ALL cross-WG payloads self-tagged in 8B atoms.
__device__ __forceinline__ void ldNC(const float* c1p,const float* c2p,const float* mzap,const float* mzbp,const float* hcp,
                                     f32x2&c1, f32x2&c2, f32x4&mzA, f32x4&mzB, float&hrC){
  asm volatile("global_load_dwordx2 %0, %5, off sc0 sc1\n\t"
               "global_load_dwordx2 %1, %6, off sc0 sc1\n\t"
               "global_load_dwordx4 %2, %7, off sc0 sc1\n\t"
               "global_load_dwordx4 %3, %8, off sc0 sc1\n\t"
               "global_load_dword %4, %9, off sc0 sc1\n\t"
               "s_waitcnt vmcnt(0)"
               : "=&v"(c1),"=&v"(c2),"=&v"(mzA),"=&v"(mzB),"=&v"(hrC)
               : "v"(c1p),"v"(c2p),"v"(mzap),"v"(mzbp),"v"(hcp) : "memory");
}
__device__ __forceinline__ void ldN2(const float* c1p,const float* c2p,const float* mzap,const float* mzbp,const float* hcp,
                                     const float* hp,
                                     f32x2&c1, f32x2&c2, f32x4&mzA, f32x4&mzB, float&hrC, f32x4&h0, f32x4&h1){
  asm volatile("global_load_dwordx2 %0, %7, off sc0 sc1\n\t"
               "global_load_dwordx2 %1, %8, off sc0 sc1\n\t"
               "global_load_dwordx4 %2, %9, off sc0 sc1\n\t"
               "global_load_dwordx4 %3, %10, off sc0 sc1\n\t"
               "global_load_dword %4, %11, off sc0 sc1\n\t"
               "global_load_dwordx4 %5, %12, off sc0 sc1\n\t"
               "global_load_dwordx4 %6, %13, off sc0 sc1\n\t"
               "s_waitcnt vmcnt(0)"
               : "=&v"(c1),"=&v"(c2),"=&v"(mzA),"=&v"(mzB),"=&v"(hrC),"=&v"(h0),"=&v"(h1)
               : "v"(c1p),"v"(c2p),"v"(mzap),"v"(mzbp),"v"(hcp),"v"(hp),"v"(hp+4) : "memory");
}
__device__ __forceinline__ void ldN3(const float* c1p,const float* c2p,const float* mzap,const float* mzbp,const float* hcp,
                                     const float* hp,const float* rp,
                                     f32x2&c1, f32x2&c2, f32x4&mzA, f32x4&mzB, float&hrC,
                                     f32x4&h0, f32x4&h1, f32x4&r0, f32x4&r1){
  asm volatile("global_load_dwordx2 %0, %9, off sc0 sc1\n\t"
               "global_load_dwordx2 %1, %10, off sc0 sc1\n\t"
               "global_load_dwordx4 %2, %11, off sc0 sc1\n\t"
               "global_load_dwordx4 %3, %12, off sc0 sc1\n\t"
               "global_load_dword %4, %13, off sc0 sc1\n\t"
               "global_load_dwordx4 %5, %14, off sc0 sc1\n\t"
               "global_load_dwordx4 %6, %15, off sc0 sc1\n\t"
               "global_load_dwordx4 %7, %16, off sc0 sc1\n\t"
               "global_load_dwordx4 %8, %17, off sc0 sc1\n\t"
               "s_waitcnt vmcnt(0)"
               : "=&v"(c1),"=&v"(c2),"=&v"(mzA),"=&v"(mzB),"=&v"(hrC),
                 "=&v"(h0),"=&v"(h1),"=&v"(r0),"=&v"(r1)
               : "v"(c1p),"v"(c2p),"v"(mzap),"v"(mzbp),"v"(hcp),"v"(hp),"v"(hp+4),"v"(rp),"v"(rp+4)
               : "memory");
}
__device__ __forceinline__ void st_coh(float* p, float v){
  asm volatile("global_store_dword %0, %1, off sc0 sc1" :: "v"(p), "v"(v) : "memory");
}
__device__ __forceinline__ void st_coh2(float* p, f32x2 v){
  asm volatile("global_store_dwordx2 %0, %1, off sc0 sc1" :: "v"(p), "v"(v) : "memory");
}
__device__ __forceinline__ void st_cohU(u32* p, u32 v){
  asm volatile("global_store_dword %0, %1, off sc0 sc1" :: "v"(p), "v"(v) : "memory");
}
__device__ __forceinline__ void pollWait(const u32* p, u32 tgt, bool active){
  if (active) {
    int guard = 0;
    u32 v;
    do {
      asm volatile("global_load_dword %0, %1, off sc0 sc1\n\ts_waitcnt vmcnt(0)"
                   : "=&v"(v) : "v"(p) : "memory");
      if (v >= tgt) break;
      __builtin_amdgcn_s_sleep(1);
    } while (++guard < (1<<22));
  }
}
__device__ __forceinline__ void drainSyncFlag(u32* fp, u32 val, int tid){
  asm volatile("s_waitcnt vmcnt(0)" ::: "memory");
  __syncthreads();
  if (tid == 0) st_cohU(fp, val);
}

__device__ __forceinline__ bool ep8(const f32x4&a,const f32x4&b,const f32x4&c,const f32x4&d,
                                    const f32x4&e,const f32x4&f,const f32x4&g,const f32x4&h,u32 t){
  return __float_as_uint(a.y)==t && __float_as_uint(a.w)==t &&
         __float_as_uint(b.y)==t && __float_as_uint(b.w)==t &&
         __float_as_uint(c.y)==t && __float_as_uint(c.w)==t &&
         __float_as_uint(d.y)==t && __float_as_uint(d.w)==t &&
         __float_as_uint(e.y)==t && __float_as_uint(e.w)==t &&
         __float_as_uint(f.y)==t && __float_as_uint(f.w)==t &&
         __float_as_uint(g.y)==t && __float_as_uint(g.w)==t &&
         __float_as_uint(h.y)==t && __float_as_uint(h.w)==t;
}
// 6-tag check: ctx pair tags + mz {m,tag,Z,tag} half-tags (split-proof)
__device__ __forceinline__ bool tg6(const f32x2&c1,const f32x2&c2,const f32x4&mzA,const f32x4&mzB,u32 t){
  return __float_as_uint(c1.y)==t && __float_as_uint(c2.y)==t &&
         __float_as_uint(mzA.y)==t && __float_as_uint(mzA.w)==t &&
         __float_as_uint(mzB.y)==t && __float_as_uint(mzB.w)==t;
}

__device__ __forceinline__ float sigm(float x){ return 1.f/(1.f + __expf(-x)); }
__device__ __forceinline__ float tanh_f(float x){ return 1.f - 2.f/(__expf(2.f*x) + 1.f); }

__device__ __forceinline__ void cvt4(const f32x4 v, ushort4* oh, ushort4* ol){
  union { ushort4 u; _Float16 h[4]; } a, b;
  a.h[0]=(_Float16)v.x; a.h[1]=(_Float16)v.y; a.h[2]=(_Float16)v.z; a.h[3]=(_Float16)v.w;
  b.h[0]=(_Float16)(v.x-(float)a.h[0]); b.h[1]=(_Float16)(v.y-(float)a.h[1]);
  b.h[2]=(_Float16)(v.z-(float)a.h[2]); b.h[3]=(_Float16)(v.w-(float)a.h[3]);
  *oh = a.u; *ol = b.u;
}

// ================= GEMM+cell role =================
template<int KBv, int L1E, int LAYER>
__device__ void runA(SmemA* A, const Params& P, int w, int mb){
  const u16* wthi = LAYER ? P.wt1h : P.wt0h;
  const u16* wtlo = LAYER ? P.wt1l : P.wt0l;
  const float* bs = LAYER ? P.bias1 : P.bias0;
  float* rawF = LAYER ? P.raw1 : P.raw0;
  const int tid = threadIdx.x;
  const int lane = tid & 63;
  const int g = tid >> 6;
  const int RL = LAYER*32 + mb*16;

  u32* fHw = P.flags + FH_OFF + (LAYER*2 + mb)*16 + w;
  u32* fR  = P.flags + FR_OFF + 0*32 + mb*16;

  f16x8 whi[KBv], wlo[KBv];
  {
    const int cb = g*16 + w;
    #pragma unroll
    for (int kb = 0; kb < KBv; ++kb) {
      whi[kb] = *(const f16x8*)(wthi + ((size_t)(cb*KBv + kb)*64 + lane)*8);
      wlo[kb] = *(const f16x8*)(wtlo + ((size_t)(cb*KBv + kb)*64 + lane)*8);
    }
  }
  const float bias = bs[g*256 + w*16 + (lane&15)];

  for (int i = tid; i < 16*17; i += 256) ((float*)A->c)[i] = 0.f;

  for (int t = 0; t < 512; ++t) {
    const int b2a = tid >> 5, cp = tid & 31;
    const int b2b = b2a + 8;
    const int slot = (t-1) & 3;
    const float* ra = P.rr + (((size_t)(RL+b2a)*4 + slot)*256 + cp*8)*2;
    const float* rb = P.rr + (((size_t)(RL+b2b)*4 + slot)*256 + cp*8)*2;
    const u32 epoch = (u32)t;
    f32x4 G0,G1,G2,G3,G4,G5,G6,G7;

    if (LAYER == 0) {
      f32x4 xv0 = *(const f32x4*)(P.x + ((size_t)((mb*16+b2a)*512 + t))*128 + cp*4);
      f32x4 xv1 = *(const f32x4*)(P.x + ((size_t)((mb*16+b2b)*512 + t))*128 + cp*4);
      if (t > 0) {
        int gu = 0;
        for (;;) {
          ld8v(ra, ra+4, ra+8, ra+12, rb, rb+4, rb+8, rb+12, G0,G1,G2,G3,G4,G5,G6,G7);
          if (ep8(G0,G1,G2,G3,G4,G5,G6,G7, epoch)) break;
          __builtin_amdgcn_s_sleep(1);
          if (++gu > (1<<20)) break;
        }
      } else {
        G0=G1=G2=G3=G4=G5=G6=G7=(f32x4){0.f,0.f,0.f,0.f};
      }
      cvt4(xv0, (ushort4*)&A->hi[b2a][cp*4], (ushort4*)&A->lo[b2a][cp*4]);
      cvt4(xv1, (ushort4*)&A->hi[b2b][cp*4], (ushort4*)&A->lo[b2b][cp*4]);
    } else {
      if (tid < 16) pollWait(fR + tid, (u32)(t+1), true);
      __syncthreads();
      const float* r0 = P.ref0 + ((size_t)((mb*16+b2a)*512 + t))*256 + cp*8;
      const float* r1 = P.ref0 + ((size_t)((mb*16+b2b)*512 + t))*256 + cp*8;
      f32x4 rv0, rv1, rv2, rv3;
      if (t > 0) {
        int gu = 0;
        for (;;) {
          ld12v(r0, r0+4, r1, r1+4, ra, ra+4, ra+8, ra+12, rb, rb+4, rb+8, rb+12,
                rv0, rv1, rv2, rv3, G0,G1,G2,G3,G4,G5,G6,G7);
          if (ep8(G0,G1,G2,G3,G4,G5,G6,G7, epoch)) break;
          __builtin_amdgcn_s_sleep(1);
          if (++gu > (1<<20)) break;
        }
      } else {
        ld4v(r0, r0+4, r1, r1+4, rv0, rv1, rv2, rv3);
        G0=G1=G2=G3=G4=G5=G6=G7=(f32x4){0.f,0.f,0.f,0.f};
      }
      cvt4(rv0, (ushort4*)&A->hi[b2a][cp*8],   (ushort4*)&A->lo[b2a][cp*8]);
      cvt4(rv1, (ushort4*)&A->hi[b2a][cp*8+4], (ushort4*)&A->lo[b2a][cp*8+4]);
      cvt4(rv2, (ushort4*)&A->hi[b2b][cp*8],   (ushort4*)&A->lo[b2b][cp*8]);
      cvt4(rv3, (ushort4*)&A->hi[b2b][cp*8+4], (ushort4*)&A->lo[b2b][cp*8+4]);
    }
    {
      const f32x4 hv0 = {G0.x,G0.z,G1.x,G1.z};
      const f32x4 hv1 = {G2.x,G2.z,G3.x,G3.z};
      const f32x4 hv2 = {G4.x,G4.z,G5.x,G5.z};
      const f32x4 hv3 = {G6.x,G6.z,G7.x,G7.z};
      cvt4(hv0, (ushort4*)&A->hi[b2a][L1E + cp*8],   (ushort4*)&A->lo[b2a][L1E + cp*8]);
      cvt4(hv1, (ushort4*)&A->hi[b2a][L1E + cp*8+4], (ushort4*)&A->lo[b2a][L1E + cp*8+4]);
      cvt4(hv2, (ushort4*)&A->hi[b2b][L1E + cp*8],   (ushort4*)&A->lo[b2b][L1E + cp*8]);
      cvt4(hv3, (ushort4*)&A->hi[b2b][L1E + cp*8+4], (ushort4*)&A->lo[b2b][L1E + cp*8+4]);
    }
    __syncthreads();
    f32x4 accA = {0.f,0.f,0.f,0.f}, accB = {0.f,0.f,0.f,0.f};
    const int ar = lane & 15;
    const int ks = (lane >> 4) * 8;
    #pragma unroll
    for (int kb = 0; kb < KBv; ++kb) {
      f16x8 ah = *(const f16x8*)(&A->hi[ar][kb*32 + ks]);
      f16x8 al = *(const f16x8*)(&A->lo[ar][kb*32 + ks]);
      accA = __builtin_amdgcn_mfma_f32_16x16x32_f16(ah, whi[kb], accA, 0,0,0);
      accB = __builtin_amdgcn_mfma_f32_16x16x32_f16(al, whi[kb], accB, 0,0,0);
      accA = __builtin_amdgcn_mfma_f32_16x16x32_f16(ah, wlo[kb], accA, 0,0,0);
      accB = __builtin_amdgcn_mfma_f32_16x16x32_f16(al, wlo[kb], accB, 0,0,0);
    }
    #pragma unroll
    for (int r = 0; r < 4; ++r)
      A->gates[g][(lane>>4)*4 + r][lane&15] = accA[r] + accB[r] + bias;
    __syncthreads();
    {
      const int bl = tid >> 4, hl = tid & 15;
      const float gi = A->gates[0][bl][hl];
      const float gf = A->gates[1][bl][hl];
      const float gg = A->gates[2][bl][hl];
      const float go = A->gates[3][bl][hl];
      const float iv = sigm(gi);
      const float fv = sigm(gf);
      const float gv = tanh_f(gg);
      const float ov = sigm(go);
      const float c = fv * A->c[bl][hl] + iv * gv;
      A->c[bl][hl] = c;
      const float hr = ov * tanh_f(c);
      const int bg = mb*16 + bl;
      f32x2 tag = { hr, __uint_as_float((u32)(t+1)) };
      st_coh2(P.rr + (((size_t)(RL+bl)*4 + (t&3))*256 + w*16 + hl)*2, tag);
      st_coh(rawF + ((size_t)(bg*512 + t))*256 + w*16 + hl, hr);
      if (t == 511) {
        P.out[HS_OFF + (LAYER*32 + bg)*256 + w*16 + hl] = hr;
        P.out[CS_OFF + (LAYER*32 + bg)*256 + w*16 + hl] = c;
      }
    }
    drainSyncFlag(fHw, (u32)(t+1), tid);
  }
}

// ================= merged scorer+combiner role =================
// WG = (l, b, q). Every scorer replicates the combine of step tC = tS-1.
// Cross-scorer partials are fully self-tagged (ctx {v,tag}; mz {m,tag,Z,tag}
// as two 8B atoms) -> fused retry-load, no flag edge, no mz ordering hazard.
__device__ void runS(SmemS* S, const Params& P, int l, int b, int q){
  float* rawF = l ? P.raw1 : P.raw0;
  const int tid = threadIdx.x;
  const int sg = tid >> 5, li = tid & 31;
  const int wsg = (tid >> 6) << 1;
  const int mb = b >> 4;
  const int o1 = (q+1)%3, o2 = (q+2)%3;
  u32* fH  = P.flags + FH_OFF + (l*2 + mb)*16;
  u32* fRb = P.flags + FR_OFF + l*32 + b;
  const size_t l32b = (size_t)(l*32 + b);

  float pm = -1e30f, pZ = 0.f, pc = 0.f;   // own partial (prev step)

  f32x4 rawA[NSLOT], rawB[NSLOT], refA[NSLOT], refB[NSLOT];
  #pragma unroll
  for (int sl = 0; sl < NSLOT; ++sl) {
    rawA[sl] = (f32x4){0.f,0.f,0.f,0.f}; rawB[sl] = (f32x4){0.f,0.f,0.f,0.f};
    refA[sl] = (f32x4){0.f,0.f,0.f,0.f}; refB[sl] = (f32x4){0.f,0.f,0.f,0.f};
  }

  for (int tS = 1; tS <= 512; ++tS) {
    const int tC = tS - 1;
    const bool doS = (tS <= 511);
    const bool gRaw = doS && (tC % 3 == q);

    // ---- poll h-row flags (GEMM). Partials arrive via data tags. ----
    if (tid < 16) pollWait(fH + tid, (u32)(doS ? tS+1 : 512), true);
    __syncthreads();

    const float* hp = rawF + ((size_t)(b*512 + tS))*256 + li*8;
    const float* rp = rawF + ((size_t)(b*512 + tC))*256 + li*8;
    f32x4 nr0, nr1, h0, h1;
    float ho;

    if (tC == 0) {
      float hrC;
      ld1s(rawF + (size_t)(b*512)*256 + tid, hrC);
      ho = hrC;
      S->hoSh[tid] = ho;
      if (q == 0) {
        if (l == 0) st_coh(P.ref0 + (size_t)(b*512)*256 + tid, ho);
        else        P.out[(size_t)(b*512)*256 + tid] = ho;
      }
      __syncthreads();
      if (gRaw) ld4v(rp, rp+4, hp, hp+4, nr0, nr1, h0, h1);
      else      ld2v(hp, hp+4, h0, h1);
      if (q == 0 && l == 0) drainSyncFlag(fRb, 1u, tid);
    } else {
      const float* c1p  = P.ctxr + (((l32b*8 + (tC&7))*3 + o1)*256 + tid)*2;
      const float* c2p  = P.ctxr + (((l32b*8 + (tC&7))*3 + o2)*256 + tid)*2;
      const float* mzap = P.mzT + ((l32b*8 + (tC&7))*3 + o1)*4;
      const float* mzbp = P.mzT + ((l32b*8 + (tC&7))*3 + o2)*4;
      const float* hcp  = rawF + ((size_t)(b*512 + tC))*256 + tid;
      float hrC;
      f32x2 c1t, c2t;
      f32x4 mzA, mzB;
      const u32 tagC = (u32)tC;
      int gu = 0;
      if (doS) {
        if (gRaw) {
          for (;;) {
            ldN3(c1p, c2p, mzap, mzbp, hcp, hp, rp, c1t, c2t, mzA, mzB, hrC, h0, h1, nr0, nr1);
            if (tg6(c1t, c2t, mzA, mzB, tagC)) break;
            __builtin_amdgcn_s_sleep(1);
            if (++gu > (1<<21)) break;
          }
        } else {
          for (;;) {
            ldN2(c1p, c2p, mzap, mzbp, hcp, hp, c1t, c2t, mzA, mzB, hrC, h0, h1);
            if (tg6(c1t, c2t, mzA, mzB, tagC)) break;
            __builtin_amdgcn_s_sleep(1);
            if (++gu > (1<<21)) break;
          }
        }
      } else {
        for (;;) {
          ldNC(c1p, c2p, mzap, mzbp, hcp, c1t, c2t, mzA, mzB, hrC);
          if (tg6(c1t, c2t, mzA, mzB, tagC)) break;
          __builtin_amdgcn_s_sleep(1);
          if (++gu > (1<<21)) break;
        }
      }
      // thread-local combine (m1=mzA.x, Z1=mzA.z, m2=mzB.x, Z2=mzB.z)
      const float m1 = mzA.x, Z1 = mzA.z;
      const float m2 = mzB.x, Z2 = mzB.z;
      const float M  = fmaxf(pm, fmaxf(m1, m2));
      const float e0 = __expf(pm - M), e1 = __expf(m1 - M), e2 = __expf(m2 - M);
      const float Zt = pZ*e0 + Z1*e1 + Z2*e2;
      const float ctxs = pc*e0 + c1t.x*e1 + c2t.x*e2;
      ho = hrC + ctxs / Zt;
      S->hoSh[tid] = ho;
      if (q == 0) {
        if (l == 0) st_coh(P.ref0 + ((size_t)(b*512 + tC))*256 + tid, ho);
        else        P.out[((size_t)(b*512 + tC))*256 + tid] = ho;
      }
      __syncthreads();
      if (q == 0 && l == 0) drainSyncFlag(fRb, (u32)(tC+1), tid);
    }

    // ---- owner commits raw(tC) + ho(tC) into register history ----
    if (gRaw) {
      const int iN = tC / 3;
      const f32x4 f0 = *(const f32x4*)&S->hoSh[li*8];
      const f32x4 f1 = *(const f32x4*)&S->hoSh[li*8 + 4];
      if (sg == (iN & 7)) {
        const int slN = iN >> 3;
        #pragma unroll
        for (int sl = 0; sl < NSLOT; ++sl)
          if (sl == slN) { rawA[sl] = nr0; rawB[sl] = nr1; refA[sl] = f0; refB[sl] = f1; }
      }
    }

    // ---- score step tS + publish self-tagged partials ----
    if (doS) {
      const int n = (tS-1 >= q) ? ((tS-1-q)/3 + 1) : 0;
      #pragma unroll
      for (int sl = 0; sl < NSLOT; ++sl) {
        if (sl*8 + wsg < n) {
          const int i = sl*8 + sg;
          float sum = rawA[sl].x*h0.x + rawA[sl].y*h0.y + rawA[sl].z*h0.z + rawA[sl].w*h0.w
                    + rawB[sl].x*h1.x + rawB[sl].y*h1.y + rawB[sl].z*h1.z + rawB[sl].w*h1.w;
          #pragma unroll
          for (int mm = 16; mm; mm >>= 1) sum += __shfl_xor(sum, mm, 32);
          if (i < n && li == 0) S->sc[i] = sum * 0.0625f;
        }
      }
      __syncthreads();
      if (tid < 64) {
        const float s0 = (tid     < n) ? S->sc[tid]     : -1e30f;
        const float s1 = (tid+64  < n) ? S->sc[tid+64]  : -1e30f;
        const float s2 = (tid+128 < n) ? S->sc[tid+128] : -1e30f;
        float mx = fmaxf(s0, fmaxf(s1, s2));
        #pragma unroll
        for (int mm = 32; mm; mm >>= 1) mx = fmaxf(mx, __shfl_xor(mx, mm, 64));
        const float e0 = (tid     < n) ? __expf(s0 - mx) : 0.f;
        const float e1 = (tid+64  < n) ? __expf(s1 - mx) : 0.f;
        const float e2 = (tid+128 < n) ? __expf(s2 - mx) : 0.f;
        if (tid     < n) S->wv[tid]     = e0;
        if (tid+64  < n) S->wv[tid+64]  = e1;
        if (tid+128 < n) S->wv[tid+128] = e2;
        float zs = e0 + e1 + e2;
        #pragma unroll
        for (int mm = 32; mm; mm >>= 1) zs += __shfl_xor(zs, mm, 64);
        if (tid == 0) { S->red[0] = mx; S->red[1] = zs; }
      }
      __syncthreads();
      const float m = S->red[0], Zs = S->red[1];
      f32x4 a0 = {0.f,0.f,0.f,0.f}, a1 = {0.f,0.f,0.f,0.f};
      #pragma unroll
      for (int sl = 0; sl < NSLOT; ++sl) {
        if (sl*8 + wsg < n) {
          const int i = sl*8 + sg;
          if (i < n) {
            const float wv = S->wv[i];
            a0.x += wv*refA[sl].x; a0.y += wv*refA[sl].y; a0.z += wv*refA[sl].z; a0.w += wv*refA[sl].w;
            a1.x += wv*refB[sl].x; a1.y += wv*refB[sl].y; a1.z += wv*refB[sl].z; a1.w += wv*refB[sl].w;
          }
        }
      }
      *(f32x4*)&S->redC[sg][li*8]     = a0;
      *(f32x4*)&S->redC[sg][li*8 + 4] = a1;
      __syncthreads();
      float cacc = 0.f;
      #pragma unroll
      for (int g2 = 0; g2 < 8; ++g2) cacc += S->redC[g2][tid];

      // publish: every store carries its own tag in the same 8B atom
      const float tagF = __uint_as_float((u32)tS);
      if (tid == 0) {
        float* mzw = P.mzT + ((l32b*8 + (tS&7))*3 + q)*4;
        st_coh2(mzw + 0, (f32x2){ m,  tagF });
        st_coh2(mzw + 2, (f32x2){ Zs, tagF });
      }
      st_coh2(P.ctxr + (((l32b*8 + (tS&7))*3 + q)*256 + tid)*2, (f32x2){ cacc, tagF });
      pm = m; pZ = Zs; pc = cacc;
    }
  }
}

__attribute__((amdgpu_waves_per_eu(1, 1)))
__global__ void __launch_bounds__(256) mainK(Params P){
  __shared__ Smem sm;
  const int blk = blockIdx.x;
  if (blk < 64) {
    const int l = blk >> 5, r = blk & 31, w = r >> 1, mb = r & 1;
    if (l == 0) runA<12,128,0>(&sm.a, P, w, mb);
    else        runA<16,256,1>(&sm.a, P, w, mb);
  } else {
    const int a = blk - 64, q = a >> 6, lb = a & 63, l = lb >> 5, b = lb & 31;
    runS(&sm.s, P, l, b, q);
  }
}

// ---- prep: weights (Dekker split), bias, zero flags + all tagged rings ----
__global__ void prepK(const float* Wih0, const float* Whh0, const float* bih0, const float* bhh0,
                      const float* Wih1, const float* Whh1, const float* bih1, const float* bhh1,
                      u16* wt0h, u16* wt0l, u16* wt1h, u16* wt1l,
                      float* bias0, float* bias1, u32* flags, float* rr, float* ctxr, float* mzT)
{
  const int np = gridDim.x * blockDim.x;
  const int g0 = blockIdx.x * blockDim.x + threadIdx.x;
  for (int i = g0; i < 64*12*512; i += np) {
    const int cb = i / (12*512), rem = i % (12*512);
    const int kb = rem / 512, r2 = rem % 512;
    const int lane = r2 >> 3, e = r2 & 7;
    const int j = cb*16 + (lane & 15);
    const int k = kb*32 + ((lane >> 4) << 3) + e;
    const float v = (k < 128) ? Wih0[j*128 + k] : Whh0[j*256 + (k - 128)];
    _Float16 h = (_Float16)v; _Float16 lo = (_Float16)(v - (float)h);
    u16 hb, lb; __builtin_memcpy(&hb,&h,2); __builtin_memcpy(&lb,&lo,2);
    wt0h[i] = hb; wt0l[i] = lb;
  }
  for (int i = g0; i < 64*16*512; i += np) {
    const int cb = i / (16*512), rem = i % (16*512);
    const int kb = rem / 512, r2 = rem % 512;
    const int lane = r2 >> 3, e = r2 & 7;
    const int j = cb*16 + (lane & 15);
    const int k = kb*32 + ((lane >> 4) << 3) + e;
    const float v = (k < 256) ? Wih1[j*256 + k] : Whh1[j*256 + (k - 256)];
    _Float16 h = (_Float16)v; _Float16 lo = (_Float16)(v - (float)h);
    u16 hb, lb; __builtin_memcpy(&hb,&h,2); __builtin_memcpy(&lb,&lo,2);
    wt1h[i] = hb; wt1l[i] = lb;
  }
  for (int i = g0; i < 1024; i += np) { bias0[i] = bih0[i] + bhh0[i]; bias1[i] = bih1[i] + bhh1[i]; }
  for (int i = g0; i < 1024; i += np) flags[i] = 0u;
  for (int i = g0; i < 64*4*256*2; i += np) rr[i] = 0.f;
  for (int i = g0; i < 64*8*3*256*2; i += np) ctxr[i] = 0.f;
  for (int i = g0; i < 64*8*3*4; i += np) mzT[i] = 0.f;
}

extern "C" void kernel_launch(void* const* d_in, const int* in_sizes, int n_in,
                              void* d_out, int out_size, void* d_ws, size_t ws_size,
                              hipStream_t stream)
{
  const float* x    = (const float*)d_in[0];
  const float* Wih0 = (const float*)d_in[1];
  const float* Whh0 = (const float*)d_in[2];
  const float* bih0 = (const float*)d_in[3];
  const float* bhh0 = (const float*)d_in[4];
  const float* Wih1 = (const float*)d_in[5];
  const float* Whh1 = (const float*)d_in[6];
  const float* bih1 = (const float*)d_in[7];
  const float* bhh1 = (const float*)d_in[8];

  char* base = (char*)d_ws;
  size_t off = 0;
  auto carve = [&](size_t bytes)->char* { char* p = base + off; off = (off + bytes + 255) & ~(size_t)255; return p; };
  u16*   wt0h  = (u16*)  carve((size_t)64*12*512*2);
  u16*   wt0l  = (u16*)  carve((size_t)64*12*512*2);
  u16*   wt1h  = (u16*)  carve((size_t)64*16*512*2);
  u16*   wt1l  = (u16*)  carve((size_t)64*16*512*2);
  float* bias0 = (float*)carve(1024*4);
  float* bias1 = (float*)carve(1024*4);
  float* raw0  = (float*)carve((size_t)32*512*256*4);
  float* ref0  = (float*)carve((size_t)32*512*256*4);
  float* raw1  = (float*)carve((size_t)32*512*256*4);
  float* ctxr  = (float*)carve((size_t)2*32*8*3*256*2*4);   // tagged float2
  float* mzT   = (float*)carve((size_t)2*32*8*3*4*4);       // tagged {m,t,Z,t}
  u32*   flags = (u32*)  carve(1024*4);
  float* rr    = (float*)carve((size_t)64*4*256*2*4);
  if (off > ws_size) return;  // workspace too small -> fail loudly

  prepK<<<dim3(1024), dim3(256), 0, stream>>>(Wih0,Whh0,bih0,bhh0,Wih1,Whh1,bih1,bhh1,
                                              wt0h,wt0l,wt1h,wt1l,bias0,bias1,flags,rr,ctxr,mzT);

  Params P;
  P.wt0h=wt0h; P.wt0l=wt0l; P.wt1h=wt1h; P.wt1l=wt1l;
  P.bias0=bias0; P.bias1=bias1; P.x=x;
  P.raw0=raw0; P.ref0=ref0; P.raw1=raw1;
  P.rr=rr; P.mzT=mzT; P.ctxr=ctxr; P.flags=flags; P.out=(float*)d_out;

  void* args[] = { &P };
  hipError_t e = hipLaunchCooperativeKernel((void*)mainK, dim3(NBLK), dim3(256), args, 0, stream);
  if (e != hipSuccess) {
    mainK<<<dim3(NBLK), dim3(256), 0, stream>>>(P);
  }
}